// Round 2
// baseline (814.829 us; speedup 1.0000x reference)
//
#include <hip/hip_runtime.h>

#define N_ROWS 65536
#define DIM 512       // NDIM == K == 512
#define MKNOTS 200
#define KT 16         // spline k-cols per block: 16 floats = one 64B line per row
#define NCELL 768     // cells over [-4,8], cell = 1/64; knot gap >= 0.0201 -> <=1 knot/cell
#define TILE 256      // spline rows per pass (= threads)
#define TPB 4         // passes per block
#define NKT (DIM / KT)

typedef _Float16 f16x8 __attribute__((ext_vector_type(8)));
typedef _Float16 f16x4 __attribute__((ext_vector_type(4)));
typedef float f32x4 __attribute__((ext_vector_type(4)));
typedef unsigned int u32x4 __attribute__((ext_vector_type(4)));

__device__ inline void gload16(const void* g, void* l) {
  __builtin_amdgcn_global_load_lds(
      (const __attribute__((address_space(1))) void*)g,
      (__attribute__((address_space(3))) void*)l,
      16, 0, 0);
}

// ---------------------------------------------------------------------------
// GEMM (unchanged — passing): C = A * Bt^T (+ addsrc), f16 MFMA,
// S3 = hi/lo split-3 for fp32-quality accumulation.
// ---------------------------------------------------------------------------
template <bool S3, bool ADDSRC>
__global__ __launch_bounds__(256)
void gemm_k(const _Float16* __restrict__ Ah, const _Float16* __restrict__ Al,
            const _Float16* __restrict__ Bth, const _Float16* __restrict__ Btl,
            const float* __restrict__ addsrc, float* __restrict__ C)
{
  __shared__ alignas(16) _Float16 smem[S3 ? 16384 : 8192];
  _Float16* sAh = smem;            // 128*32
  _Float16* sBh = smem + 4096;     // 128*32 (Bt rows = n)
  _Float16* sAl = S3 ? smem + 8192  : smem;
  _Float16* sBl = S3 ? smem + 12288 : smem;

  const int tid  = threadIdx.x;
  const int bm   = blockIdx.x * 128;
  const int bn   = blockIdx.y * 128;
  const int wm   = ((tid >> 6) >> 1) * 64;
  const int wn   = ((tid >> 6) & 1) * 64;
  const int lane = tid & 63;
  const int lm   = lane & 15;
  const int quad = lane >> 4;
  const int sr   = tid >> 2;        // staging row 0..63
  const int sc   = (tid & 3) * 8;   // staging col chunk (8 f16 = 16B)

  const _Float16* gAh = Ah  + (size_t)(bm + sr) * DIM + sc;
  const _Float16* gBh = Bth + (size_t)(bn + sr) * DIM + sc;
  const _Float16* gAl = S3 ? (Al  + (size_t)(bm + sr) * DIM + sc) : gAh;
  const _Float16* gBl = S3 ? (Btl + (size_t)(bn + sr) * DIM + sc) : gBh;

  f32x4 acc[4][4] = {};

  for (int k0 = 0; k0 < DIM; k0 += 32) {
    gload16(gAh + k0,               sAh + tid * 8);
    gload16(gAh + k0 + 64 * DIM,    sAh + 2048 + tid * 8);
    gload16(gBh + k0,               sBh + tid * 8);
    gload16(gBh + k0 + 64 * DIM,    sBh + 2048 + tid * 8);
    if constexpr (S3) {
      gload16(gAl + k0,             sAl + tid * 8);
      gload16(gAl + k0 + 64 * DIM,  sAl + 2048 + tid * 8);
      gload16(gBl + k0,             sBl + tid * 8);
      gload16(gBl + k0 + 64 * DIM,  sBl + 2048 + tid * 8);
    }
    __syncthreads();

    f16x8 a_h[4], b_h[4], a_l[4], b_l[4];
    #pragma unroll
    for (int i = 0; i < 4; ++i) {
      a_h[i] = *(const f16x8*)&sAh[(wm + i * 16 + lm) * 32 + quad * 8];
      b_h[i] = *(const f16x8*)&sBh[(wn + i * 16 + lm) * 32 + quad * 8];
      if constexpr (S3) {
        a_l[i] = *(const f16x8*)&sAl[(wm + i * 16 + lm) * 32 + quad * 8];
        b_l[i] = *(const f16x8*)&sBl[(wn + i * 16 + lm) * 32 + quad * 8];
      }
    }
    #pragma unroll
    for (int i = 0; i < 4; ++i)
      #pragma unroll
      for (int j = 0; j < 4; ++j) {
        acc[i][j] = __builtin_amdgcn_mfma_f32_16x16x32_f16(a_h[i], b_h[j], acc[i][j], 0, 0, 0);
        if constexpr (S3) {
          acc[i][j] = __builtin_amdgcn_mfma_f32_16x16x32_f16(a_h[i], b_l[j], acc[i][j], 0, 0, 0);
          acc[i][j] = __builtin_amdgcn_mfma_f32_16x16x32_f16(a_l[i], b_h[j], acc[i][j], 0, 0, 0);
        }
      }
    __syncthreads();
  }

  // C/D layout (verified m89/m91): col = lane&15, row = quad*4 + reg
  #pragma unroll
  for (int i = 0; i < 4; ++i)
    #pragma unroll
    for (int j = 0; j < 4; ++j)
      #pragma unroll
      for (int r = 0; r < 4; ++r) {
        const int row = bm + wm + i * 16 + quad * 4 + r;
        const int col = bn + wn + j * 16 + lm;
        const size_t idx = (size_t)row * DIM + col;
        float v = acc[i][j][r];
        if constexpr (ADDSRC) v += addsrc[idx];
        C[idx] = v;
      }
}

// ---------------------------------------------------------------------------
// fp32 -> f16 hi/lo split of data
// ---------------------------------------------------------------------------
__global__ __launch_bounds__(256)
void conv_data_k(const float* __restrict__ in, _Float16* __restrict__ hi,
                 _Float16* __restrict__ lo)
{
  const size_t i = ((size_t)blockIdx.x * 256 + threadIdx.x) * 4;
  const float4 v = *reinterpret_cast<const float4*>(in + i);
  f16x4 h, l;
  h.x = (_Float16)v.x; l.x = (_Float16)(v.x - (float)h.x);
  h.y = (_Float16)v.y; l.y = (_Float16)(v.y - (float)h.y);
  h.z = (_Float16)v.z; l.z = (_Float16)(v.z - (float)h.z);
  h.w = (_Float16)v.w; l.w = (_Float16)(v.w - (float)h.w);
  *reinterpret_cast<f16x4*>(hi + i) = h;
  *reinterpret_cast<f16x4*>(lo + i) = l;
}

__global__ __launch_bounds__(256)
void conv_A_k(const float* __restrict__ A, _Float16* __restrict__ Ah,
              _Float16* __restrict__ Al, _Float16* __restrict__ ATh,
              _Float16* __restrict__ ATl)
{
  const int i = blockIdx.x * 256 + threadIdx.x;
  const int r = i >> 9, c = i & 511;
  const float v = A[i];
  const _Float16 h = (_Float16)v;
  const _Float16 l = (_Float16)(v - (float)h);
  Ah[i] = h; Al[i] = l;
  ATh[c * 512 + r] = h; ATl[c * 512 + r] = l;
}

// ---------------------------------------------------------------------------
// Spline prep: pkG[k][j] = {x, y, d, 0}; bucketG[k][c] = #{x_j <= -4 + c/64}.
// Cell 1/64 = 0.015625 < min knot gap 0.0201 -> at most 1 knot per cell.
// ---------------------------------------------------------------------------
__global__ __launch_bounds__(256)
void prep_k(const float* __restrict__ xx, const float* __restrict__ yy,
            const float* __restrict__ dd, float4* __restrict__ pkG,
            unsigned char* __restrict__ bucketG)
{
  __shared__ float xr[MKNOTS];
  const int k = blockIdx.x, tid = threadIdx.x;
  if (tid < MKNOTS) xr[tid] = xx[k * MKNOTS + tid];
  __syncthreads();
  if (tid < MKNOTS) {
    const float x0 = xr[tid];
    const float y0 = yy[k * MKNOTS + tid];
    const float d0 = dd[k * MKNOTS + tid];
    pkG[k * MKNOTS + tid] = float4{x0, y0, d0, 0.f};
  }
  for (int c = tid; c < NCELL; c += 256) {
    const float cl = -4.f + (float)c * 0.015625f;
    int lo = 0, hi = MKNOTS;
    while (lo < hi) { const int mid = (lo + hi) >> 1; if (xr[mid] <= cl) lo = mid + 1; else hi = mid; }
    bucketG[k * NCELL + c] = (unsigned char)lo;
  }
}

// ---------------------------------------------------------------------------
// RQ spline v6: KT=16 thread-per-row. Each thread's row slice is one full
// 64B line -> 4x dwordx4, zero over-fetch (R2-verified granularity). z is
// 32B contiguous per row -> 2x 16B stores, amplification-free (R2 WRITE
// evidence). Knots SoA in LDS (x f32 / y f32 / d f16, 31.4 KB): scalar
// gathers conflict only mod-32 (vs AoS float4 mod-8). rdx via rcpf
// (R2-proven accuracy). 1-probe bucket search, single __logf.
// ---------------------------------------------------------------------------
__global__ __launch_bounds__(256, 4)
void spline_k(const float* __restrict__ data0, const float4* __restrict__ pkG,
              const unsigned char* __restrict__ bucketG,
              _Float16* __restrict__ zH, float* __restrict__ ppart)
{
  __shared__ float sX[KT * 201 + 1];     // 200 knots + 1 pad per row
  __shared__ float sY[KT * 201 + 1];
  __shared__ _Float16 sD[KT * 201 + 2];

  const int kBase = blockIdx.x * KT;
  const int nBase = blockIdx.y * (TILE * TPB);
  const int tid = threadIdx.x;

  for (int i = tid; i < KT * MKNOTS; i += 256) {
    const int r = i / MKNOTS, c = i - r * MKNOTS;
    const float4 v = pkG[(kBase + r) * MKNOTS + c];
    sX[r * 201 + c] = v.x;
    sY[r * 201 + c] = v.y;
    sD[r * 201 + c] = (_Float16)v.z;
  }
  if (tid < KT) {                        // pad entry (only read when discarded)
    sX[tid * 201 + 200] = 1e30f;
    sY[tid * 201 + 200] = 0.f;
    sD[tid * 201 + 200] = (_Float16)1.f;
  }
  __syncthreads();

  const unsigned char* bRow = bucketG + (size_t)kBase * NCELL;
  const float* xp0 = data0 + (size_t)(nBase + tid) * DIM + kBase;

  float4 v0 = *(const float4*)xp0;
  float4 v1 = *(const float4*)(xp0 + 4);
  float4 v2 = *(const float4*)(xp0 + 8);
  float4 v3 = *(const float4*)(xp0 + 12);

  #pragma unroll
  for (int t = 0; t < TPB; ++t) {
    const float x16[16] = {v0.x, v0.y, v0.z, v0.w, v1.x, v1.y, v1.z, v1.w,
                           v2.x, v2.y, v2.z, v2.w, v3.x, v3.y, v3.z, v3.w};
    if (t + 1 < TPB) {                   // prefetch next pass
      const float* xp = xp0 + (size_t)(t + 1) * TILE * DIM;
      v0 = *(const float4*)xp;
      v1 = *(const float4*)(xp + 4);
      v2 = *(const float4*)(xp + 8);
      v3 = *(const float4*)(xp + 12);
    }

    float acc = 0.f;
    float zprev = 0.f;
    unsigned int zw[8];
    #pragma unroll
    for (int j = 0; j < KT; ++j) {
      const float x = x16[j];

      int c = (int)(x * 64.f + 256.f);   // floor((x+4)*64) for x > -4
      c = min(max(c, 0), NCELL - 1);
      const int cnt = (int)bRow[j * NCELL + c];     // #knots <= cell-left, >= 1
      const int q = min(cnt, MKNOTS - 1);
      const float xq = sX[j * 201 + q];             // <=1 knot/cell -> 1 cmp refine
      const int b = min(cnt + (xq < x ? 1 : 0), MKNOTS) - 1;   // searchsorted-1, 0..199

      const float xk  = sX[j * 201 + b];
      const float xk1 = sX[j * 201 + b + 1];
      const float yk  = sY[j * 201 + b];
      const float yk1 = sY[j * 201 + b + 1];
      const float dk  = (float)sD[j * 201 + b];
      const float dk1 = (float)sD[j * 201 + b + 1];

      const float rdx = __builtin_amdgcn_rcpf(xk1 - xk);
      const float dy  = yk1 - yk;
      const float s   = dy * rdx;
      float xi = (x - xk) * rdx;
      xi = fminf(fmaxf(xi, 0.f), 1.f);
      const float xi1 = 1.f - xi;
      const float g = xi * xi1;
      const float den = s + (dk1 + dk - 2.f * s) * g;
      const float rden = __builtin_amdgcn_rcpf(den);
      const float y_in = yk + dy * (s * xi * xi + dk * g) * rden;
      const float dnum = dk1 * xi * xi + 2.f * s * g + dk * xi1 * xi1;

      const bool edge = (x <= -4.f) || (b == MKNOTS - 1);  // below || above
      const float larg = edge ? dk : (s * s * dnum) * (rden * rden);
      acc += __logf(larg);                                  // single transcendental
      const float y = edge ? (yk + dk * (x - xk)) : y_in;

      const float z = y - x;
      if (j & 1) {
        union { _Float16 h[2]; unsigned int u; } pk2;
        pk2.h[0] = (_Float16)zprev; pk2.h[1] = (_Float16)z;
        zw[j >> 1] = pk2.u;
      } else {
        zprev = z;
      }
    }

    const int row = nBase + t * TILE + tid;
    ppart[(size_t)blockIdx.x * N_ROWS + row] = acc;
    union { unsigned int w[4]; u32x4 v4; } za, zb;
    za.w[0] = zw[0]; za.w[1] = zw[1]; za.w[2] = zw[2]; za.w[3] = zw[3];
    zb.w[0] = zw[4]; zb.w[1] = zw[5]; zb.w[2] = zw[6]; zb.w[3] = zw[7];
    u32x4* dst = (u32x4*)(zH + (size_t)row * DIM + kBase);  // 32B aligned
    dst[0] = za.v4;
    dst[1] = zb.v4;
  }
}

// logj[n] = sum over NKT k-tiles of ppart[kt][n]
__global__ __launch_bounds__(256)
void reduce_k(const float* __restrict__ ppart, float* __restrict__ logj)
{
  const int n = blockIdx.x * 256 + threadIdx.x;
  float a = 0.f;
  #pragma unroll
  for (int t = 0; t < NKT; ++t) a += ppart[(size_t)t * N_ROWS + n];
  logj[n] = a;
}

// ---------------------------------------------------------------------------
extern "C" void kernel_launch(void* const* d_in, const int* in_sizes, int n_in,
                              void* d_out, int out_size, void* d_ws, size_t ws_size,
                              hipStream_t stream)
{
  const float* data  = (const float*)d_in[0];
  const float* A     = (const float*)d_in[1];
  const float* xx    = (const float*)d_in[2];
  const float* yy    = (const float*)d_in[3];
  const float* delta = (const float*)d_in[4];

  float* out  = (float*)d_out;                       // N_ROWS * DIM
  float* logj = out + (size_t)N_ROWS * DIM;          // N_ROWS

  // workspace layout (~258 MiB)
  _Float16* dHi = (_Float16*)d_ws;                   // 64 MiB
  _Float16* dLo = dHi + (size_t)N_ROWS * DIM;        // 64 MiB
  _Float16* Ah  = dLo + (size_t)N_ROWS * DIM;        // 512 KiB each
  _Float16* Al  = Ah + 512 * 512;
  _Float16* ATh = Al + 512 * 512;
  _Float16* ATl = ATh + 512 * 512;
  float* data0  = (float*)(ATl + 512 * 512);         // 128 MiB
  _Float16* zH  = dHi;                               // alias: dHi dead after GEMM1
  // spline tables + partials alias dLo (dead after GEMM1): 1.6M + 384K + 8.4M
  float4* pkG = (float4*)dLo;
  unsigned char* bucketG = (unsigned char*)(pkG + 512 * MKNOTS);
  float* ppart = (float*)(bucketG + 512 * NCELL);

  conv_A_k<<<1024, 256, 0, stream>>>(A, Ah, Al, ATh, ATl);
  conv_data_k<<<(N_ROWS * DIM) / (256 * 4), 256, 0, stream>>>(data, dHi, dLo);

  // data0 = data @ A  (split-3 f16, fp32-quality)
  gemm_k<true, false><<<dim3(N_ROWS / 128, DIM / 128), 256, 0, stream>>>(
      dHi, dLo, ATh, ATl, nullptr, data0);

  prep_k<<<512, 256, 0, stream>>>(xx, yy, delta, pkG, bucketG);

  spline_k<<<dim3(DIM / KT, N_ROWS / (TILE * TPB)), 256, 0, stream>>>(
      data0, pkG, bucketG, zH, ppart);

  reduce_k<<<N_ROWS / 256, 256, 0, stream>>>(ppart, logj);

  // out = data + z @ A^T  (plain f16)
  gemm_k<false, true><<<dim3(N_ROWS / 128, DIM / 128), 256, 0, stream>>>(
      zH, nullptr, Ah, nullptr, data, out);
}

// Round 3
// 689.638 us; speedup vs baseline: 1.1815x; 1.1815x over previous
//
#include <hip/hip_runtime.h>

#define N_ROWS 65536
#define DIM 512       // NDIM == K == 512
#define MKNOTS 200
#define KT 16         // spline k-cols per block
#define NCELL 768     // cells over [-4,8], cell = 1/64; knot gap >= 0.0201 -> <=1 knot/cell
#define TPB 4         // passes of 256 rows per block
#define NKT (DIM / KT)

typedef _Float16 f16x8 __attribute__((ext_vector_type(8)));
typedef _Float16 f16x4 __attribute__((ext_vector_type(4)));
typedef float f32x4 __attribute__((ext_vector_type(4)));

__device__ inline void gload16(const void* g, void* l) {
  __builtin_amdgcn_global_load_lds(
      (const __attribute__((address_space(1))) void*)g,
      (__attribute__((address_space(3))) void*)l,
      16, 0, 0);
}

// ---------------------------------------------------------------------------
// GEMM: C[m][n_ldC] = A * Bt^T (+ addsrc), f16 MFMA, S3 = split-3 fp32-quality.
// ldC runtime so GEMM1 can emit data0 TRANSPOSED (k-major) via operand swap:
// data0T = A^T @ data^T -> A-operand = ATh, B-operand = dHi, ldC = 65536.
// C-write stays 64B-dense chunks (16 lanes x 4B along cols).
// ---------------------------------------------------------------------------
template <bool S3, bool ADDSRC>
__global__ __launch_bounds__(256)
void gemm_k(const _Float16* __restrict__ Ah, const _Float16* __restrict__ Al,
            const _Float16* __restrict__ Bth, const _Float16* __restrict__ Btl,
            const float* __restrict__ addsrc, float* __restrict__ C,
            const int ldC)
{
  __shared__ alignas(16) _Float16 smem[S3 ? 16384 : 8192];
  _Float16* sAh = smem;            // 128*32
  _Float16* sBh = smem + 4096;     // 128*32 (Bt rows = n)
  _Float16* sAl = S3 ? smem + 8192  : smem;
  _Float16* sBl = S3 ? smem + 12288 : smem;

  const int tid  = threadIdx.x;
  const int bm   = blockIdx.x * 128;
  const int bn   = blockIdx.y * 128;
  const int wm   = ((tid >> 6) >> 1) * 64;
  const int wn   = ((tid >> 6) & 1) * 64;
  const int lane = tid & 63;
  const int lm   = lane & 15;
  const int quad = lane >> 4;
  const int sr   = tid >> 2;        // staging row 0..63
  const int sc   = (tid & 3) * 8;   // staging col chunk (8 f16 = 16B)

  const _Float16* gAh = Ah  + (size_t)(bm + sr) * DIM + sc;
  const _Float16* gBh = Bth + (size_t)(bn + sr) * DIM + sc;
  const _Float16* gAl = S3 ? (Al  + (size_t)(bm + sr) * DIM + sc) : gAh;
  const _Float16* gBl = S3 ? (Btl + (size_t)(bn + sr) * DIM + sc) : gBh;

  f32x4 acc[4][4] = {};

  for (int k0 = 0; k0 < DIM; k0 += 32) {
    gload16(gAh + k0,               sAh + tid * 8);
    gload16(gAh + k0 + 64 * DIM,    sAh + 2048 + tid * 8);
    gload16(gBh + k0,               sBh + tid * 8);
    gload16(gBh + k0 + 64 * DIM,    sBh + 2048 + tid * 8);
    if constexpr (S3) {
      gload16(gAl + k0,             sAl + tid * 8);
      gload16(gAl + k0 + 64 * DIM,  sAl + 2048 + tid * 8);
      gload16(gBl + k0,             sBl + tid * 8);
      gload16(gBl + k0 + 64 * DIM,  sBl + 2048 + tid * 8);
    }
    __syncthreads();

    f16x8 a_h[4], b_h[4], a_l[4], b_l[4];
    #pragma unroll
    for (int i = 0; i < 4; ++i) {
      a_h[i] = *(const f16x8*)&sAh[(wm + i * 16 + lm) * 32 + quad * 8];
      b_h[i] = *(const f16x8*)&sBh[(wn + i * 16 + lm) * 32 + quad * 8];
      if constexpr (S3) {
        a_l[i] = *(const f16x8*)&sAl[(wm + i * 16 + lm) * 32 + quad * 8];
        b_l[i] = *(const f16x8*)&sBl[(wn + i * 16 + lm) * 32 + quad * 8];
      }
    }
    #pragma unroll
    for (int i = 0; i < 4; ++i)
      #pragma unroll
      for (int j = 0; j < 4; ++j) {
        acc[i][j] = __builtin_amdgcn_mfma_f32_16x16x32_f16(a_h[i], b_h[j], acc[i][j], 0, 0, 0);
        if constexpr (S3) {
          acc[i][j] = __builtin_amdgcn_mfma_f32_16x16x32_f16(a_h[i], b_l[j], acc[i][j], 0, 0, 0);
          acc[i][j] = __builtin_amdgcn_mfma_f32_16x16x32_f16(a_l[i], b_h[j], acc[i][j], 0, 0, 0);
        }
      }
    __syncthreads();
  }

  // C/D layout (verified m89/m91): col = lane&15, row = quad*4 + reg
  #pragma unroll
  for (int i = 0; i < 4; ++i)
    #pragma unroll
    for (int j = 0; j < 4; ++j)
      #pragma unroll
      for (int r = 0; r < 4; ++r) {
        const int row = bm + wm + i * 16 + quad * 4 + r;
        const int col = bn + wn + j * 16 + lm;
        const size_t idx = (size_t)row * ldC + col;
        float v = acc[i][j][r];
        if constexpr (ADDSRC) v += addsrc[idx];
        C[idx] = v;
      }
}

// ---------------------------------------------------------------------------
// fp32 -> f16 hi/lo split of data
// ---------------------------------------------------------------------------
__global__ __launch_bounds__(256)
void conv_data_k(const float* __restrict__ in, _Float16* __restrict__ hi,
                 _Float16* __restrict__ lo)
{
  const size_t i = ((size_t)blockIdx.x * 256 + threadIdx.x) * 4;
  const float4 v = *reinterpret_cast<const float4*>(in + i);
  f16x4 h, l;
  h.x = (_Float16)v.x; l.x = (_Float16)(v.x - (float)h.x);
  h.y = (_Float16)v.y; l.y = (_Float16)(v.y - (float)h.y);
  h.z = (_Float16)v.z; l.z = (_Float16)(v.z - (float)h.z);
  h.w = (_Float16)v.w; l.w = (_Float16)(v.w - (float)h.w);
  *reinterpret_cast<f16x4*>(hi + i) = h;
  *reinterpret_cast<f16x4*>(lo + i) = l;
}

__global__ __launch_bounds__(256)
void conv_A_k(const float* __restrict__ A, _Float16* __restrict__ Ah,
              _Float16* __restrict__ Al, _Float16* __restrict__ ATh,
              _Float16* __restrict__ ATl)
{
  const int i = blockIdx.x * 256 + threadIdx.x;
  const int r = i >> 9, c = i & 511;
  const float v = A[i];
  const _Float16 h = (_Float16)v;
  const _Float16 l = (_Float16)(v - (float)h);
  Ah[i] = h; Al[i] = l;
  ATh[c * 512 + r] = h; ATl[c * 512 + r] = l;
}

// ---------------------------------------------------------------------------
// Spline prep: pkG[k][j] = {x, y, d_j, d_{j+1}}; bucketG[k][c] = #{x_j <= -4+c/64}.
// Cell 1/64 = 0.015625 < min knot gap 0.0201 -> at most 1 knot per cell.
// ---------------------------------------------------------------------------
__global__ __launch_bounds__(256)
void prep_k(const float* __restrict__ xx, const float* __restrict__ yy,
            const float* __restrict__ dd, float4* __restrict__ pkG,
            unsigned char* __restrict__ bucketG)
{
  __shared__ float xr[MKNOTS];
  const int k = blockIdx.x, tid = threadIdx.x;
  if (tid < MKNOTS) xr[tid] = xx[k * MKNOTS + tid];
  __syncthreads();
  if (tid < MKNOTS) {
    const float x0 = xr[tid];
    const float y0 = yy[k * MKNOTS + tid];
    const float d0 = dd[k * MKNOTS + tid];
    const float d1 = (tid < MKNOTS - 1) ? dd[k * MKNOTS + tid + 1] : 1.f;
    pkG[k * MKNOTS + tid] = float4{x0, y0, d0, d1};
  }
  for (int c = tid; c < NCELL; c += 256) {
    const float cl = -4.f + (float)c * 0.015625f;
    int lo = 0, hi = MKNOTS;
    while (lo < hi) { const int mid = (lo + hi) >> 1; if (xr[mid] <= cl) lo = mid + 1; else hi = mid; }
    bucketG[k * NCELL + c] = (unsigned char)lo;
  }
}

// ---------------------------------------------------------------------------
// RQ spline v7: thread-per-n over k-major data0T -> every global load is a
// fully coalesced 256B wave instruction (no read staging at all). zH stores
// bounce through a 9.2KB LDS buffer into the baseline's proven-clean coop
// shape (wave instr = 8 rows x 32B contiguous). Knots: float2 xy + packed
// f16 d-pairs -> 4 aligned LDS gathers/eval. v6's validated eval (1-probe
// bucket search, single __logf). LDS 47.8 KB -> 3 blocks/CU.
// ---------------------------------------------------------------------------
__global__ __launch_bounds__(256, 3)
void spline_k(const float* __restrict__ data0T, const float4* __restrict__ pkG,
              const unsigned char* __restrict__ bucketG,
              _Float16* __restrict__ zH, float* __restrict__ ppart)
{
  __shared__ float2 sXY[KT * 201];          // 25.7 KB
  __shared__ unsigned int sDD[KT * 201];    // 12.9 KB, packed {d[b], d[b+1]}
  __shared__ unsigned int zS[256 * 9];      // 9.2 KB, pad 9 -> 2-way (free)

  const int kBase = blockIdx.x * KT;
  const int nBase = blockIdx.y * (256 * TPB);
  const int tid = threadIdx.x;

  for (int i = tid; i < KT * MKNOTS; i += 256) {
    const int r = i / MKNOTS, c = i - r * MKNOTS;
    const float4 v = pkG[(kBase + r) * MKNOTS + c];
    sXY[r * 201 + c] = float2{v.x, v.y};
    union { _Float16 h[2]; unsigned int u; } dp;
    dp.h[0] = (_Float16)v.z; dp.h[1] = (_Float16)v.w;
    sDD[r * 201 + c] = dp.u;
  }
  if (tid < KT) {                           // pad entry (read only when discarded)
    sXY[tid * 201 + 200] = float2{1e30f, 0.f};
    union { _Float16 h[2]; unsigned int u; } dp;
    dp.h[0] = (_Float16)1.f; dp.h[1] = (_Float16)1.f;
    sDD[tid * 201 + 200] = dp.u;
  }
  __syncthreads();

  const unsigned char* bRow = bucketG + (size_t)kBase * NCELL;

  float xc[KT], xn[KT];
  #pragma unroll
  for (int j = 0; j < KT; ++j)
    xc[j] = data0T[((size_t)(kBase + j) << 16) + nBase + tid];

  for (int t = 0; t < TPB; ++t) {
    const int n = nBase + t * 256 + tid;
    if (t + 1 < TPB) {                      // prefetch next pass (coalesced)
      #pragma unroll
      for (int j = 0; j < KT; ++j)
        xn[j] = data0T[((size_t)(kBase + j) << 16) + n + 256];
    }

    float acc = 0.f;
    float zprev = 0.f;
    unsigned int zw[8];
    #pragma unroll
    for (int j = 0; j < KT; ++j) {
      const float x = xc[j];

      int c = (int)(x * 64.f + 256.f);      // floor((x+4)*64) for x > -4
      c = min(max(c, 0), NCELL - 1);
      const int cnt = (int)bRow[j * NCELL + c];    // #knots <= cell-left, >= 1
      const int q = min(cnt, MKNOTS - 1);
      const float xq = sXY[j * 201 + q].x;         // <=1 knot/cell -> 1 cmp refine
      const int b = min(cnt + (xq < x ? 1 : 0), MKNOTS) - 1;  // searchsorted-1, 0..199

      const float2 p0 = sXY[j * 201 + b];          // {xk, yk}
      const float2 p1 = sXY[j * 201 + b + 1];      // {xk1, yk1}
      union { unsigned int u; _Float16 h[2]; } dp;
      dp.u = sDD[j * 201 + b];
      const float dk  = (float)dp.h[0];
      const float dk1 = (float)dp.h[1];

      const float rdx = __builtin_amdgcn_rcpf(p1.x - p0.x);
      const float dy  = p1.y - p0.y;
      const float s   = dy * rdx;
      float xi = (x - p0.x) * rdx;
      xi = fminf(fmaxf(xi, 0.f), 1.f);
      const float xi1 = 1.f - xi;
      const float g = xi * xi1;
      const float den = s + (dk1 + dk - 2.f * s) * g;
      const float rden = __builtin_amdgcn_rcpf(den);
      const float y_in = p0.y + dy * (s * xi * xi + dk * g) * rden;
      const float dnum = dk1 * xi * xi + 2.f * s * g + dk * xi1 * xi1;

      const bool edge = (x <= -4.f) || (b == MKNOTS - 1);  // below || above
      const float larg = edge ? dk : (s * s * dnum) * (rden * rden);
      acc += __logf(larg);                                  // single transcendental
      const float y = edge ? (p0.y + dk * (x - p0.x)) : y_in;

      const float z = y - x;
      if (j & 1) {
        union { _Float16 h[2]; unsigned int u; } pk2;
        pk2.h[0] = (_Float16)zprev; pk2.h[1] = (_Float16)z;
        zw[j >> 1] = pk2.u;
      } else {
        zprev = z;
      }
    }
    #pragma unroll
    for (int j = 0; j < KT; ++j) xc[j] = xn[j];

    ppart[(size_t)blockIdx.x * N_ROWS + n] = acc;

    __syncthreads();                        // zS reads of pass t-1 complete
    #pragma unroll
    for (int w = 0; w < 8; ++w) zS[tid * 9 + w] = zw[w];
    __syncthreads();

    // coop z store: wave instr = 8 rows x 32B contiguous (proven amp-free)
    const int w = tid & 7;
    #pragma unroll
    for (int ri = 0; ri < 8; ++ri) {
      const int r = ri * 32 + (tid >> 3);
      *(unsigned int*)(zH + (size_t)(nBase + t * 256 + r) * DIM + kBase + w * 2)
          = zS[r * 9 + w];
    }
  }
}

// logj[n] = sum over NKT k-tiles of ppart[kt][n]
__global__ __launch_bounds__(256)
void reduce_k(const float* __restrict__ ppart, float* __restrict__ logj)
{
  const int n = blockIdx.x * 256 + threadIdx.x;
  float a = 0.f;
  #pragma unroll
  for (int t = 0; t < NKT; ++t) a += ppart[(size_t)t * N_ROWS + n];
  logj[n] = a;
}

// ---------------------------------------------------------------------------
extern "C" void kernel_launch(void* const* d_in, const int* in_sizes, int n_in,
                              void* d_out, int out_size, void* d_ws, size_t ws_size,
                              hipStream_t stream)
{
  const float* data  = (const float*)d_in[0];
  const float* A     = (const float*)d_in[1];
  const float* xx    = (const float*)d_in[2];
  const float* yy    = (const float*)d_in[3];
  const float* delta = (const float*)d_in[4];

  float* out  = (float*)d_out;                       // N_ROWS * DIM
  float* logj = out + (size_t)N_ROWS * DIM;          // N_ROWS

  // workspace layout (~258 MiB)
  _Float16* dHi = (_Float16*)d_ws;                   // 64 MiB
  _Float16* dLo = dHi + (size_t)N_ROWS * DIM;        // 64 MiB
  _Float16* Ah  = dLo + (size_t)N_ROWS * DIM;        // 512 KiB each
  _Float16* Al  = Ah + 512 * 512;
  _Float16* ATh = Al + 512 * 512;
  _Float16* ATl = ATh + 512 * 512;
  float* data0T = (float*)(ATl + 512 * 512);         // 128 MiB, k-major [512][65536]
  _Float16* zH  = dHi;                               // alias: dHi dead after GEMM1
  // spline tables + partials alias dLo (dead after GEMM1): 1.6M + 384K + 8.4M
  float4* pkG = (float4*)dLo;
  unsigned char* bucketG = (unsigned char*)(pkG + 512 * MKNOTS);
  float* ppart = (float*)(bucketG + 512 * NCELL);

  conv_A_k<<<1024, 256, 0, stream>>>(A, Ah, Al, ATh, ATl);
  conv_data_k<<<(N_ROWS * DIM) / (256 * 4), 256, 0, stream>>>(data, dHi, dLo);

  // data0T = A^T @ data^T  (operand-swapped split-3 f16, k-major output)
  gemm_k<true, false><<<dim3(DIM / 128, N_ROWS / 128), 256, 0, stream>>>(
      ATh, ATl, dHi, dLo, nullptr, data0T, N_ROWS);

  prep_k<<<512, 256, 0, stream>>>(xx, yy, delta, pkG, bucketG);

  spline_k<<<dim3(DIM / KT, N_ROWS / (256 * TPB)), 256, 0, stream>>>(
      data0T, pkG, bucketG, zH, ppart);

  reduce_k<<<N_ROWS / 256, 256, 0, stream>>>(ppart, logj);

  // out = data + z @ A^T  (plain f16)
  gemm_k<false, true><<<dim3(N_ROWS / 128, DIM / 128), 256, 0, stream>>>(
      zH, nullptr, Ah, nullptr, data, out, DIM);
}

// Round 4
// 606.664 us; speedup vs baseline: 1.3431x; 1.1368x over previous
//
#include <hip/hip_runtime.h>

#define N_ROWS 65536
#define DIM 512       // NDIM == K == 512
#define MKNOTS 200
#define KT 16         // spline k-cols per block
#define NCELL 768     // cells over [-4,8], cell = 1/64; knot gap >= 0.0201 -> <=1 knot/cell
#define TILE 256      // spline rows per tile (= threads)
#define TPB 4         // tiles per block
#define NKT (DIM / KT)

typedef _Float16 f16x8 __attribute__((ext_vector_type(8)));
typedef _Float16 f16x4 __attribute__((ext_vector_type(4)));
typedef float f32x4 __attribute__((ext_vector_type(4)));

__device__ inline void gload16(const void* g, void* l) {
  __builtin_amdgcn_global_load_lds(
      (const __attribute__((address_space(1))) void*)g,
      (__attribute__((address_space(3))) void*)l,
      16, 0, 0);
}

// ---------------------------------------------------------------------------
// GEMM (baseline, unchanged — passing): C = A * Bt^T (+ addsrc), f16 MFMA,
// S3 = hi/lo split-3 for fp32-quality accumulation.
// ---------------------------------------------------------------------------
template <bool S3, bool ADDSRC>
__global__ __launch_bounds__(256)
void gemm_k(const _Float16* __restrict__ Ah, const _Float16* __restrict__ Al,
            const _Float16* __restrict__ Bth, const _Float16* __restrict__ Btl,
            const float* __restrict__ addsrc, float* __restrict__ C)
{
  __shared__ alignas(16) _Float16 smem[S3 ? 16384 : 8192];
  _Float16* sAh = smem;            // 128*32
  _Float16* sBh = smem + 4096;     // 128*32 (Bt rows = n)
  _Float16* sAl = S3 ? smem + 8192  : smem;
  _Float16* sBl = S3 ? smem + 12288 : smem;

  const int tid  = threadIdx.x;
  const int bm   = blockIdx.x * 128;
  const int bn   = blockIdx.y * 128;
  const int wm   = ((tid >> 6) >> 1) * 64;
  const int wn   = ((tid >> 6) & 1) * 64;
  const int lane = tid & 63;
  const int lm   = lane & 15;
  const int quad = lane >> 4;
  const int sr   = tid >> 2;        // staging row 0..63
  const int sc   = (tid & 3) * 8;   // staging col chunk (8 f16 = 16B)

  const _Float16* gAh = Ah  + (size_t)(bm + sr) * DIM + sc;
  const _Float16* gBh = Bth + (size_t)(bn + sr) * DIM + sc;
  const _Float16* gAl = S3 ? (Al  + (size_t)(bm + sr) * DIM + sc) : gAh;
  const _Float16* gBl = S3 ? (Btl + (size_t)(bn + sr) * DIM + sc) : gBh;

  f32x4 acc[4][4] = {};

  for (int k0 = 0; k0 < DIM; k0 += 32) {
    gload16(gAh + k0,               sAh + tid * 8);
    gload16(gAh + k0 + 64 * DIM,    sAh + 2048 + tid * 8);
    gload16(gBh + k0,               sBh + tid * 8);
    gload16(gBh + k0 + 64 * DIM,    sBh + 2048 + tid * 8);
    if constexpr (S3) {
      gload16(gAl + k0,             sAl + tid * 8);
      gload16(gAl + k0 + 64 * DIM,  sAl + 2048 + tid * 8);
      gload16(gBl + k0,             sBl + tid * 8);
      gload16(gBl + k0 + 64 * DIM,  sBl + 2048 + tid * 8);
    }
    __syncthreads();

    f16x8 a_h[4], b_h[4], a_l[4], b_l[4];
    #pragma unroll
    for (int i = 0; i < 4; ++i) {
      a_h[i] = *(const f16x8*)&sAh[(wm + i * 16 + lm) * 32 + quad * 8];
      b_h[i] = *(const f16x8*)&sBh[(wn + i * 16 + lm) * 32 + quad * 8];
      if constexpr (S3) {
        a_l[i] = *(const f16x8*)&sAl[(wm + i * 16 + lm) * 32 + quad * 8];
        b_l[i] = *(const f16x8*)&sBl[(wn + i * 16 + lm) * 32 + quad * 8];
      }
    }
    #pragma unroll
    for (int i = 0; i < 4; ++i)
      #pragma unroll
      for (int j = 0; j < 4; ++j) {
        acc[i][j] = __builtin_amdgcn_mfma_f32_16x16x32_f16(a_h[i], b_h[j], acc[i][j], 0, 0, 0);
        if constexpr (S3) {
          acc[i][j] = __builtin_amdgcn_mfma_f32_16x16x32_f16(a_h[i], b_l[j], acc[i][j], 0, 0, 0);
          acc[i][j] = __builtin_amdgcn_mfma_f32_16x16x32_f16(a_l[i], b_h[j], acc[i][j], 0, 0, 0);
        }
      }
    __syncthreads();
  }

  // C/D layout (verified m89/m91): col = lane&15, row = quad*4 + reg
  #pragma unroll
  for (int i = 0; i < 4; ++i)
    #pragma unroll
    for (int j = 0; j < 4; ++j)
      #pragma unroll
      for (int r = 0; r < 4; ++r) {
        const int row = bm + wm + i * 16 + quad * 4 + r;
        const int col = bn + wn + j * 16 + lm;
        const size_t idx = (size_t)row * DIM + col;
        float v = acc[i][j][r];
        if constexpr (ADDSRC) v += addsrc[idx];
        C[idx] = v;
      }
}

// ---------------------------------------------------------------------------
// fp32 -> f16 hi/lo split of data
// ---------------------------------------------------------------------------
__global__ __launch_bounds__(256)
void conv_data_k(const float* __restrict__ in, _Float16* __restrict__ hi,
                 _Float16* __restrict__ lo)
{
  const size_t i = ((size_t)blockIdx.x * 256 + threadIdx.x) * 4;
  const float4 v = *reinterpret_cast<const float4*>(in + i);
  f16x4 h, l;
  h.x = (_Float16)v.x; l.x = (_Float16)(v.x - (float)h.x);
  h.y = (_Float16)v.y; l.y = (_Float16)(v.y - (float)h.y);
  h.z = (_Float16)v.z; l.z = (_Float16)(v.z - (float)h.z);
  h.w = (_Float16)v.w; l.w = (_Float16)(v.w - (float)h.w);
  *reinterpret_cast<f16x4*>(hi + i) = h;
  *reinterpret_cast<f16x4*>(lo + i) = l;
}

__global__ __launch_bounds__(256)
void conv_A_k(const float* __restrict__ A, _Float16* __restrict__ Ah,
              _Float16* __restrict__ Al, _Float16* __restrict__ ATh,
              _Float16* __restrict__ ATl)
{
  const int i = blockIdx.x * 256 + threadIdx.x;
  const int r = i >> 9, c = i & 511;
  const float v = A[i];
  const _Float16 h = (_Float16)v;
  const _Float16 l = (_Float16)(v - (float)h);
  Ah[i] = h; Al[i] = l;
  ATh[c * 512 + r] = h; ATl[c * 512 + r] = l;
}

// ---------------------------------------------------------------------------
// Spline prep: pkG[k][j] = {x, y, d, 0}; bucketG[k][c] = #{x_j <= -4 + c/64}.
// Cell 1/64 = 0.015625 < min knot gap 0.0201 -> at most 1 knot per cell.
// ---------------------------------------------------------------------------
__global__ __launch_bounds__(256)
void prep_k(const float* __restrict__ xx, const float* __restrict__ yy,
            const float* __restrict__ dd, float4* __restrict__ pkG,
            unsigned char* __restrict__ bucketG)
{
  __shared__ float xr[MKNOTS];
  const int k = blockIdx.x, tid = threadIdx.x;
  if (tid < MKNOTS) xr[tid] = xx[k * MKNOTS + tid];
  __syncthreads();
  if (tid < MKNOTS) {
    const float x0 = xr[tid];
    const float y0 = yy[k * MKNOTS + tid];
    const float d0 = dd[k * MKNOTS + tid];
    pkG[k * MKNOTS + tid] = float4{x0, y0, d0, 0.f};
  }
  for (int c = tid; c < NCELL; c += 256) {
    const float cl = -4.f + (float)c * 0.015625f;
    int lo = 0, hi = MKNOTS;
    while (lo < hi) { const int mid = (lo + hi) >> 1; if (xr[mid] <= cl) lo = mid + 1; else hi = mid; }
    bucketG[k * NCELL + c] = (unsigned char)lo;
  }
}

// ---------------------------------------------------------------------------
// RQ spline v8: baseline R0's I/O shell verbatim (measured amp-free: FETCH
// 134MB / WRITE 72MB) -- full-line staged x-tile reads, in-place z packing
// in xT, coop 8-lane x 32B stores -- with the thrice-validated cheap eval
// grafted in: 1-probe bucket search (1 knot/cell), float2 xy + f16 d LDS,
// rcpf, single selected __logf. LDS 48.4 KB -> 3 blocks/CU.
// ---------------------------------------------------------------------------
__global__ __launch_bounds__(256)
void spline_k(const float* __restrict__ data0, const float4* __restrict__ pkG,
              const unsigned char* __restrict__ bucketG,
              _Float16* __restrict__ zH, float* __restrict__ ppart)
{
  __shared__ float2 sXY[KT * 201];      // 25.7 KB: {x,y} per knot + 1 pad/row
  __shared__ _Float16 sD[KT * 201 + 2]; // 6.4 KB
  __shared__ float xT[TILE * 17];       // 17.4 KB: 16 x's + pad; z overwrites words 0..7

  const int kBase = blockIdx.x * KT;
  const int nBase = blockIdx.y * (TILE * TPB);
  const int tid = threadIdx.x;

  for (int i = tid; i < KT * MKNOTS; i += 256) {
    const int r = i / MKNOTS, c = i - r * MKNOTS;
    const float4 v = pkG[(kBase + r) * MKNOTS + c];
    sXY[r * 201 + c] = float2{v.x, v.y};
    sD[r * 201 + c] = (_Float16)v.z;
  }
  if (tid < KT) {                       // pad knot: read only when discarded
    sXY[tid * 201 + 200] = float2{1e30f, 0.f};
    sD[tid * 201 + 200] = (_Float16)1.f;
  }
  __syncthreads();

  for (int tile = 0; tile < TPB; ++tile) {
    const int n0 = nBase + tile * TILE;

    // stage x tile: full-line coalesced (4 lanes x float4 per row) [amp-free]
    #pragma unroll
    for (int rr = 0; rr < 4; ++rr) {
      const int r = rr * 64 + (tid >> 2);
      const float4 v = *((const float4*)(data0 + (size_t)(n0 + r) * DIM + kBase) + (tid & 3));
      float* dst = &xT[r * 17 + (tid & 3) * 4];
      dst[0] = v.x; dst[1] = v.y; dst[2] = v.z; dst[3] = v.w;
    }
    __syncthreads();

    // compute: thread -> row n0+tid, 16 evals, register logd accumulation
    float acc = 0.f;
    float zprev = 0.f;
    #pragma unroll 4
    for (int j = 0; j < KT; ++j) {
      const float x = xT[tid * 17 + j];

      int c = (int)(x * 64.f + 256.f);  // floor((x+4)*64) for x > -4
      c = min(max(c, 0), NCELL - 1);
      const int cnt = (int)bucketG[(kBase + j) * NCELL + c];  // #knots <= cell-left, >=1
      const int q = min(cnt, MKNOTS - 1);
      const float xq = sXY[j * 201 + q].x;          // <=1 knot/cell -> 1 cmp refine
      const int b = min(cnt + (xq < x ? 1 : 0), MKNOTS) - 1;  // searchsorted-1, 0..199

      const float2 p0 = sXY[j * 201 + b];           // {xk, yk}
      const float2 p1 = sXY[j * 201 + b + 1];       // {xk1, yk1}
      const float dk  = (float)sD[j * 201 + b];
      const float dk1 = (float)sD[j * 201 + b + 1];

      const float rdx = __builtin_amdgcn_rcpf(p1.x - p0.x);
      const float dy  = p1.y - p0.y;
      const float s   = dy * rdx;
      float xi = (x - p0.x) * rdx;
      xi = fminf(fmaxf(xi, 0.f), 1.f);
      const float xi1 = 1.f - xi;
      const float g = xi * xi1;
      const float den = s + (dk1 + dk - 2.f * s) * g;
      const float rden = __builtin_amdgcn_rcpf(den);
      const float y_in = p0.y + dy * (s * xi * xi + dk * g) * rden;
      const float dnum = dk1 * xi * xi + 2.f * s * g + dk * xi1 * xi1;

      const bool edge = (x <= -4.f) || (b == MKNOTS - 1);  // below || above
      const float larg = edge ? dk : (s * s * dnum) * (rden * rden);
      acc += __logf(larg);                                  // single transcendental
      const float y = edge ? (p0.y + dk * (x - p0.x)) : y_in;

      const float z = y - x;
      if (j & 1) {
        union { _Float16 h[2]; unsigned int u; } pk2;
        pk2.h[0] = (_Float16)zprev; pk2.h[1] = (_Float16)z;
        ((unsigned int*)xT)[tid * 17 + (j >> 1)] = pk2.u;   // word (j>>1) < j: safe in-place
      } else {
        zprev = z;
      }
    }
    ppart[(size_t)blockIdx.x * N_ROWS + n0 + tid] = acc;
    __syncthreads();

    // coop z store: 8 lanes x 4B cover a row's 32B contiguous (baseline shape)
    const int w = tid & 7;
    #pragma unroll
    for (int ri = 0; ri < 8; ++ri) {
      const int r = ri * 32 + (tid >> 3);
      const unsigned int zz = ((const unsigned int*)xT)[r * 17 + w];
      *(unsigned int*)(zH + (size_t)(n0 + r) * DIM + kBase + w * 2) = zz;
    }
    __syncthreads();
  }
}

// logj[n] = sum over NKT k-tiles of ppart[kt][n]
__global__ __launch_bounds__(256)
void reduce_k(const float* __restrict__ ppart, float* __restrict__ logj)
{
  const int n = blockIdx.x * 256 + threadIdx.x;
  float a = 0.f;
  #pragma unroll
  for (int t = 0; t < NKT; ++t) a += ppart[(size_t)t * N_ROWS + n];
  logj[n] = a;
}

// ---------------------------------------------------------------------------
extern "C" void kernel_launch(void* const* d_in, const int* in_sizes, int n_in,
                              void* d_out, int out_size, void* d_ws, size_t ws_size,
                              hipStream_t stream)
{
  const float* data  = (const float*)d_in[0];
  const float* A     = (const float*)d_in[1];
  const float* xx    = (const float*)d_in[2];
  const float* yy    = (const float*)d_in[3];
  const float* delta = (const float*)d_in[4];

  float* out  = (float*)d_out;                       // N_ROWS * DIM
  float* logj = out + (size_t)N_ROWS * DIM;          // N_ROWS

  // workspace layout (~258 MiB)
  _Float16* dHi = (_Float16*)d_ws;                   // 64 MiB
  _Float16* dLo = dHi + (size_t)N_ROWS * DIM;        // 64 MiB
  _Float16* Ah  = dLo + (size_t)N_ROWS * DIM;        // 512 KiB each
  _Float16* Al  = Ah + 512 * 512;
  _Float16* ATh = Al + 512 * 512;
  _Float16* ATl = ATh + 512 * 512;
  float* data0  = (float*)(ATl + 512 * 512);         // 128 MiB
  _Float16* zH  = dHi;                               // alias: dHi dead after GEMM1
  // spline tables + partials alias dLo (dead after GEMM1): 1.6M + 384K + 8M
  float4* pkG = (float4*)dLo;
  unsigned char* bucketG = (unsigned char*)(pkG + 512 * MKNOTS);
  float* ppart = (float*)(bucketG + 512 * NCELL);

  conv_A_k<<<1024, 256, 0, stream>>>(A, Ah, Al, ATh, ATl);
  conv_data_k<<<(N_ROWS * DIM) / (256 * 4), 256, 0, stream>>>(data, dHi, dLo);

  // data0 = data @ A  (split-3 f16, fp32-quality)
  gemm_k<true, false><<<dim3(N_ROWS / 128, DIM / 128), 256, 0, stream>>>(
      dHi, dLo, ATh, ATl, nullptr, data0);

  prep_k<<<512, 256, 0, stream>>>(xx, yy, delta, pkG, bucketG);

  spline_k<<<dim3(DIM / KT, N_ROWS / (TILE * TPB)), 256, 0, stream>>>(
      data0, pkG, bucketG, zH, ppart);

  reduce_k<<<N_ROWS / 256, 256, 0, stream>>>(ppart, logj);

  // out = data + z @ A^T  (plain f16)
  gemm_k<false, true><<<dim3(N_ROWS / 128, DIM / 128), 256, 0, stream>>>(
      zH, nullptr, Ah, nullptr, data, out);
}